// Round 3
// baseline (714.348 us; speedup 1.0000x reference)
//
#include <hip/hip_runtime.h>

#define NN 50000
#define NE 800000
#define C 128
#define OUTC 64
#define BN_EPS 1e-5f
#define INVN (1.0f / 50000.0f)
#define NBLK 49   // ceil(NN/1024)
#define PLANE ((size_t)NN * 16)   // floats per channel-slice plane

// ---------------- CSR build ----------------

__global__ __launch_bounds__(256) void hist_kernel(const int* __restrict__ dstp, int* __restrict__ cnt) {
    int e = blockIdx.x * 256 + threadIdx.x;
    if (e < NE) atomicAdd(&cnt[dstp[e]], 1);
}

__global__ __launch_bounds__(256) void scan1_kernel(const int* __restrict__ cnt, int* __restrict__ rowptr,
                                                    float* __restrict__ dinv, int* __restrict__ bsum) {
    __shared__ int lds[256];
    int tid = threadIdx.x;
    int base = blockIdx.x * 1024 + tid * 4;
    int v[4];
    int s = 0;
    #pragma unroll
    for (int j = 0; j < 4; ++j) { int i = base + j; v[j] = (i < NN) ? cnt[i] : 0; s += v[j]; }
    lds[tid] = s;
    __syncthreads();
    for (int off = 1; off < 256; off <<= 1) {
        int x = (tid >= off) ? lds[tid - off] : 0;
        __syncthreads();
        lds[tid] += x;
        __syncthreads();
    }
    int excl = lds[tid] - s;
    #pragma unroll
    for (int j = 0; j < 4; ++j) {
        int i = base + j;
        if (i < NN) {
            rowptr[i] = excl;                       // local exclusive; offset added in phase 3
            dinv[i] = rsqrtf((float)(v[j] + 1));    // +1 self-loop
        }
        excl += v[j];
    }
    if (tid == 255) bsum[blockIdx.x] = lds[255];
}

__global__ __launch_bounds__(64) void scan2_kernel(int* __restrict__ bsum, int* __restrict__ rowptr) {
    int tid = threadIdx.x;
    int orig = (tid < NBLK) ? bsum[tid] : 0;
    int v = orig;
    #pragma unroll
    for (int off = 1; off < 64; off <<= 1) {
        int x = __shfl_up(v, off);
        if (tid >= off) v += x;
    }
    if (tid < NBLK) bsum[tid] = v - orig;
    if (tid == 63) rowptr[NN] = v;
}

__global__ __launch_bounds__(256) void scan3_kernel(const int* __restrict__ bsum, int* __restrict__ rowptr,
                                                    int* __restrict__ wpos) {
    int off = bsum[blockIdx.x];
    int base = blockIdx.x * 1024 + threadIdx.x * 4;
    #pragma unroll
    for (int j = 0; j < 4; ++j) {
        int i = base + j;
        if (i < NN) { int r = rowptr[i] + off; rowptr[i] = r; wpos[i] = r; }
    }
}

__global__ __launch_bounds__(256) void fill_kernel(const int* __restrict__ srcp, const int* __restrict__ dstp,
                                                   int* __restrict__ wpos, int* __restrict__ col) {
    int e = blockIdx.x * 256 + threadIdx.x;
    if (e < NE) {
        int d = dstp[e];
        int p = atomicAdd(&wpos[d], 1);
        col[p] = srcp[e];
    }
}

__global__ __launch_bounds__(256) void prep_kernel(const float* __restrict__ Wmu, const float* __restrict__ Wls,
                                                   const float* __restrict__ bmu, const float* __restrict__ bls,
                                                   float* __restrict__ Wcomb, float* __restrict__ biasc) {
    int tid = blockIdx.x * 256 + threadIdx.x;
    if (tid < 128 * 128) {
        int k = tid >> 7, c = tid & 127;
        Wcomb[tid] = (c < 64) ? Wmu[k * 64 + c] : Wls[k * 64 + (c - 64)];
    }
    if (tid < 128) biasc[tid] = (tid < 64) ? bmu[tid] : bls[tid - 64];
}

// ---------------- GEMM: [N x 128] @ [128 x 128], f32 vector ALU ----------------
// TRANS   : apply BN(from raw sums)+ReLU to A on load
// SPLIT   : write cols 0..63 -> out (+bias), 64..127 -> out2 (+bias), row-major stride 64
// RSCALE  : multiply output row by dinv[row]
// SLICEDIN: A is in sliced layout (8 planes of [NN][16]); else row-major [NN][128]
// (!SPLIT output is always sliced layout)

template<bool TRANS, bool SPLIT, bool RSCALE, bool SLICEDIN>
__global__ __launch_bounds__(256) void gemm_kernel(
    const float* __restrict__ A, const float* __restrict__ W,
    const float* __restrict__ sums, const float* __restrict__ gamma, const float* __restrict__ beta,
    const float* __restrict__ bias, const float* __restrict__ dinv,
    float* __restrict__ out, float* __restrict__ out2)
{
    __shared__ float Ws[64][128];    // 32 KB (one k-half of W)
    __shared__ float xT[128][36];    // 18 KB (transposed 32-row tile, padded)
    int tid = threadIdx.x;
    int row0 = blockIdx.x * 32;

    #pragma unroll
    for (int i = 0; i < 4; ++i) {           // stage 32x128 input tile (float4), transposed
        int idx = tid + i * 256;            // float4 index 0..1023
        int r = idx >> 5;                   // 32 float4 per row
        int k4 = (idx & 31) * 4;
        int gr = row0 + r;
        float vv[4] = {0.f, 0.f, 0.f, 0.f};
        if (gr < NN) {
            float4 v;
            if (SLICEDIN) v = *(const float4*)&A[(size_t)(k4 >> 4) * PLANE + (size_t)gr * 16 + (k4 & 15)];
            else          v = *(const float4*)&A[(size_t)gr * C + k4];
            vv[0] = v.x; vv[1] = v.y; vv[2] = v.z; vv[3] = v.w;
        }
        if (TRANS) {
            #pragma unroll
            for (int j = 0; j < 4; ++j) {
                int k = k4 + j;
                float mean = sums[k] * INVN;
                float var = fmaf(-mean, mean, sums[128 + k] * INVN);
                float sc = gamma[k] * rsqrtf(var + BN_EPS);
                float sh = fmaf(-mean, sc, beta[k]);
                vv[j] = fmaxf(fmaf(vv[j], sc, sh), 0.f);
            }
        }
        xT[k4 + 0][r] = vv[0]; xT[k4 + 1][r] = vv[1]; xT[k4 + 2][r] = vv[2]; xT[k4 + 3][r] = vv[3];
    }

    float acc[4][4] = {};
    int cg = (tid & 31) * 4;   // output col base
    int rg = (tid >> 5) * 4;   // local row base

    for (int kh = 0; kh < 2; ++kh) {
        __syncthreads();
        #pragma unroll
        for (int i = 0; i < 8; ++i) {       // stage W k-half
            int fi = tid + i * 256;         // float4 index 0..2047
            int k = fi >> 5;
            int c4 = (fi & 31) * 4;
            *(float4*)&Ws[k][c4] = *(const float4*)&W[(kh * 64 + k) * C + c4];
        }
        __syncthreads();
        #pragma unroll 8
        for (int k = 0; k < 64; ++k) {
            float4 a = *(const float4*)&xT[kh * 64 + k][rg];
            float4 b = *(const float4*)&Ws[k][cg];
            acc[0][0] = fmaf(a.x, b.x, acc[0][0]); acc[0][1] = fmaf(a.x, b.y, acc[0][1]);
            acc[0][2] = fmaf(a.x, b.z, acc[0][2]); acc[0][3] = fmaf(a.x, b.w, acc[0][3]);
            acc[1][0] = fmaf(a.y, b.x, acc[1][0]); acc[1][1] = fmaf(a.y, b.y, acc[1][1]);
            acc[1][2] = fmaf(a.y, b.z, acc[1][2]); acc[1][3] = fmaf(a.y, b.w, acc[1][3]);
            acc[2][0] = fmaf(a.z, b.x, acc[2][0]); acc[2][1] = fmaf(a.z, b.y, acc[2][1]);
            acc[2][2] = fmaf(a.z, b.z, acc[2][2]); acc[2][3] = fmaf(a.z, b.w, acc[2][3]);
            acc[3][0] = fmaf(a.w, b.x, acc[3][0]); acc[3][1] = fmaf(a.w, b.y, acc[3][1]);
            acc[3][2] = fmaf(a.w, b.z, acc[3][2]); acc[3][3] = fmaf(a.w, b.w, acc[3][3]);
        }
    }

    #pragma unroll
    for (int i = 0; i < 4; ++i) {
        int row = row0 + rg + i;
        if (row < NN) {
            float rs = RSCALE ? dinv[row] : 1.f;
            if (!SPLIT) {
                float4 o = make_float4(acc[i][0] * rs, acc[i][1] * rs, acc[i][2] * rs, acc[i][3] * rs);
                *(float4*)&out[(size_t)(cg >> 4) * PLANE + (size_t)row * 16 + (cg & 15)] = o;   // sliced
            } else {
                float* dst = (cg < 64) ? out : out2;
                int cc = cg & 63;
                float4 o = make_float4(acc[i][0] + bias[cg], acc[i][1] + bias[cg + 1],
                                       acc[i][2] + bias[cg + 2], acc[i][3] + bias[cg + 3]);
                *(float4*)&dst[(size_t)row * 64 + cc] = o;
            }
        }
    }
}

// ---------------- Sliced pull aggregation ----------------
// Block b: slice g = b&7 (-> XCD via round-robin), 4 dst rows (one per wave).
// Lane = sub*16 + c: 4 edge chains x 16 channels; shfl_down 4->1 reduce.
// !TRANS: input pre-scaled by dinv (RSCALE gemm): out = dinv[i]*(t'[i] + sum t'[s])
//  TRANS: input raw; per-element f(v) = dinv[s]*relu(BN(v)) applied inline (fused layer-3 elementwise)

template<bool TRANS>
__global__ __launch_bounds__(256) void agg_kernel(
    const float* __restrict__ t, const int* __restrict__ rowptr, const int* __restrict__ col,
    const float* __restrict__ dinv,
    const float* __restrict__ sums, const float* __restrict__ gamma, const float* __restrict__ beta,
    float* __restrict__ outb)
{
    int g = blockIdx.x & 7;
    int rb = blockIdx.x >> 3;
    int wave = threadIdx.x >> 6;
    int lane = threadIdx.x & 63;
    int row = rb * 4 + wave;
    if (row >= NN) return;
    int c = lane & 15;
    int sub = lane >> 4;
    const float* tp = t + (size_t)g * PLANE + c;
    float sc = 1.f, sh = 0.f;
    if (TRANS) {
        int ch = g * 16 + c;
        float mean = sums[ch] * INVN;
        float var = fmaf(-mean, mean, sums[128 + ch] * INVN);
        sc = gamma[ch] * rsqrtf(var + BN_EPS);
        sh = fmaf(-mean, sc, beta[ch]);
    }
    int e0 = rowptr[row], e1 = rowptr[row + 1];
    float a = 0.f;
    int e = e0 + sub;
    for (; e + 4 < e1; e += 8) {          // 2 chains in flight per lane-group
        int s0 = col[e], s1 = col[e + 4];
        float v0 = tp[(size_t)s0 * 16];
        float v1 = tp[(size_t)s1 * 16];
        if (TRANS) {
            v0 = dinv[s0] * fmaxf(fmaf(v0, sc, sh), 0.f);
            v1 = dinv[s1] * fmaxf(fmaf(v1, sc, sh), 0.f);
        }
        a += v0 + v1;
    }
    if (e < e1) {
        int s = col[e];
        float v = tp[(size_t)s * 16];
        if (TRANS) v = dinv[s] * fmaxf(fmaf(v, sc, sh), 0.f);
        a += v;
    }
    a += __shfl_down(a, 32);
    a += __shfl_down(a, 16);
    if (sub == 0) {
        float di = dinv[row];
        float v = tp[(size_t)row * 16];    // self-loop
        if (TRANS) v = di * fmaxf(fmaf(v, sc, sh), 0.f);
        a += v;
        outb[(size_t)g * PLANE + (size_t)row * 16 + c] = di * a;
    }
}

// ---------------- BatchNorm stats (sliced input) ----------------

__global__ __launch_bounds__(256) void bnstats_kernel(const float* __restrict__ h, float* __restrict__ sums) {
    int c = threadIdx.x & 127;
    int hh = threadIdx.x >> 7;
    const float* hp = h + (size_t)(c >> 4) * PLANE + (c & 15);
    float s = 0.f, sq = 0.f;
    for (int r = blockIdx.x * 2 + hh; r < NN; r += gridDim.x * 2) {
        float v = hp[(size_t)r * 16];
        s += v; sq = fmaf(v, v, sq);
    }
    __shared__ float ls[256], lq[256];
    ls[threadIdx.x] = s; lq[threadIdx.x] = sq;
    __syncthreads();
    if (hh == 0) {
        atomicAdd(&sums[c], s + ls[c + 128]);
        atomicAdd(&sums[128 + c], sq + lq[c + 128]);
    }
}

// ---------------- launch ----------------

extern "C" void kernel_launch(void* const* d_in, const int* in_sizes, int n_in,
                              void* d_out, int out_size, void* d_ws, size_t ws_size,
                              hipStream_t stream) {
    (void)in_sizes; (void)n_in; (void)out_size; (void)ws_size;
    const float* x      = (const float*)d_in[0];
    const int*   ei     = (const int*)d_in[1];
    const float* W1     = (const float*)d_in[2];
    // d_in[3] = b1: cancelled exactly by BN mean-subtraction
    const float* gamma1 = (const float*)d_in[4];
    const float* beta1  = (const float*)d_in[5];
    const float* W2     = (const float*)d_in[6];
    // d_in[7] = b2: cancelled exactly by BN
    const float* gamma2 = (const float*)d_in[8];
    const float* beta2  = (const float*)d_in[9];
    const float* Wmu    = (const float*)d_in[10];
    const float* bmu    = (const float*)d_in[11];
    const float* Wls    = (const float*)d_in[12];
    const float* bls    = (const float*)d_in[13];

    float* outmu = (float*)d_out;
    float* outls = outmu + (size_t)NN * OUTC;

    char* w = (char*)d_ws;
    size_t off = 0;
    auto alloc = [&](size_t bytes) { char* p = w + off; off = (off + bytes + 255) & ~(size_t)255; return p; };
    float* t      = (float*)alloc(sizeof(float) * NN * C);       // 25.6 MB (sliced)
    float* aggb   = (float*)alloc(sizeof(float) * NN * C);       // 25.6 MB (sliced)
    int*   cnt    = (int*)  alloc(sizeof(int) * NN);
    int*   rowptr = (int*)  alloc(sizeof(int) * (NN + 1));
    int*   wpos   = (int*)  alloc(sizeof(int) * NN);
    int*   col    = (int*)  alloc(sizeof(int) * NE);
    float* dinv   = (float*)alloc(sizeof(float) * NN);
    int*   bsum   = (int*)  alloc(sizeof(int) * 64);
    float* sums   = (float*)alloc(sizeof(float) * 512);          // [sumsA(256) | sumsB(256)]
    float* Wcomb  = (float*)alloc(sizeof(float) * C * C);
    float* biasc  = (float*)alloc(512);
    float* sumsA = sums; float* sumsB = sums + 256;

    const int* srcp = ei;
    const int* dstp = ei + NE;

    hipMemsetAsync(cnt, 0, sizeof(int) * NN, stream);
    hipMemsetAsync(sums, 0, sizeof(float) * 512, stream);

    hist_kernel<<<(NE + 255) / 256, 256, 0, stream>>>(dstp, cnt);
    scan1_kernel<<<NBLK, 256, 0, stream>>>(cnt, rowptr, dinv, bsum);
    scan2_kernel<<<1, 64, 0, stream>>>(bsum, rowptr);
    scan3_kernel<<<NBLK, 256, 0, stream>>>(bsum, rowptr, wpos);
    fill_kernel<<<(NE + 255) / 256, 256, 0, stream>>>(srcp, dstp, wpos, col);
    prep_kernel<<<64, 256, 0, stream>>>(Wmu, Wls, bmu, bls, Wcomb, biasc);

    const int GB = (NN + 31) / 32;
    const int AB = ((NN + 3) / 4) * 8;   // 4 rows/block x 8 slices

    // layer 1: t = dinv .* (x@W1) [sliced] ; aggb = aggregate ; BN1 stats
    gemm_kernel<false, false, true, false><<<GB, 256, 0, stream>>>(x, W1, nullptr, nullptr, nullptr, nullptr, dinv, t, nullptr);
    agg_kernel<false><<<AB, 256, 0, stream>>>(t, rowptr, col, dinv, nullptr, nullptr, nullptr, aggb);
    bnstats_kernel<<<400, 256, 0, stream>>>(aggb, sumsA);

    // layer 2: t = dinv .* (relu(BN1(aggb))@W2) [sliced] ; aggb = aggregate ; BN2 stats
    gemm_kernel<true, false, true, true><<<GB, 256, 0, stream>>>(aggb, W2, sumsA, gamma1, beta1, nullptr, dinv, t, nullptr);
    agg_kernel<false><<<AB, 256, 0, stream>>>(t, rowptr, col, dinv, nullptr, nullptr, nullptr, aggb);
    bnstats_kernel<<<400, 256, 0, stream>>>(aggb, sumsB);

    // heads: t = aggregate(dinv .* relu(BN2(aggb))) [fused] ; [mu|ls] = t @ [Wmu|Wls] + bias
    agg_kernel<true><<<AB, 256, 0, stream>>>(aggb, rowptr, col, dinv, sumsB, gamma2, beta2, t);
    gemm_kernel<false, true, false, true><<<GB, 256, 0, stream>>>(t, Wcomb, nullptr, nullptr, nullptr, biasc, nullptr, outmu, outls);
}

// Round 4
// 548.368 us; speedup vs baseline: 1.3027x; 1.3027x over previous
//
#include <hip/hip_runtime.h>

#define NN 50000
#define NE 800000
#define C 128
#define OUTC 64
#define BN_EPS 1e-5f
#define INVN (1.0f / 50000.0f)
#define NBLK 49   // ceil(NN/1024)
#define PLANE ((size_t)NN * 16)   // floats per channel-slice plane

// ---------------- CSR build ----------------

__global__ __launch_bounds__(256) void hist_kernel(const int* __restrict__ dstp, int* __restrict__ cnt) {
    int e = blockIdx.x * 256 + threadIdx.x;
    if (e < NE) atomicAdd(&cnt[dstp[e]], 1);
}

__global__ __launch_bounds__(256) void scan1_kernel(const int* __restrict__ cnt, int* __restrict__ rowptr,
                                                    float* __restrict__ dinv, int* __restrict__ bsum) {
    __shared__ int lds[256];
    int tid = threadIdx.x;
    int base = blockIdx.x * 1024 + tid * 4;
    int v[4];
    int s = 0;
    #pragma unroll
    for (int j = 0; j < 4; ++j) { int i = base + j; v[j] = (i < NN) ? cnt[i] : 0; s += v[j]; }
    lds[tid] = s;
    __syncthreads();
    for (int off = 1; off < 256; off <<= 1) {
        int x = (tid >= off) ? lds[tid - off] : 0;
        __syncthreads();
        lds[tid] += x;
        __syncthreads();
    }
    int excl = lds[tid] - s;
    #pragma unroll
    for (int j = 0; j < 4; ++j) {
        int i = base + j;
        if (i < NN) {
            rowptr[i] = excl;                       // local exclusive; block offset added in scan3
            dinv[i] = rsqrtf((float)(v[j] + 1));    // +1 self-loop
        }
        excl += v[j];
    }
    if (tid == 255) bsum[blockIdx.x] = lds[255];
}

// adds block offsets (inline 49-element scan of bsum), mirrors into wpos
__global__ __launch_bounds__(256) void scan3_kernel(const int* __restrict__ bsum, int* __restrict__ rowptr,
                                                    int* __restrict__ wpos) {
    __shared__ int boff;
    int tid = threadIdx.x;
    if (tid < 64) {
        int orig = (tid < NBLK) ? bsum[tid] : 0;
        int v = orig;
        #pragma unroll
        for (int off = 1; off < 64; off <<= 1) {
            int x = __shfl_up(v, off);
            if (tid >= off) v += x;
        }
        if (tid == (int)blockIdx.x) boff = v - orig;   // exclusive prefix at this block
    }
    __syncthreads();
    int off = boff;
    int base = blockIdx.x * 1024 + tid * 4;
    #pragma unroll
    for (int j = 0; j < 4; ++j) {
        int i = base + j;
        if (i < NN) { int r = rowptr[i] + off; rowptr[i] = r; wpos[i] = r; }
    }
    if (blockIdx.x == 0 && tid == 0) rowptr[NN] = NE;
}

__global__ __launch_bounds__(256) void fill_kernel(const int* __restrict__ srcp, const int* __restrict__ dstp,
                                                   int* __restrict__ wpos, int* __restrict__ col) {
    int e = blockIdx.x * 256 + threadIdx.x;
    if (e < NE) {
        int d = dstp[e];
        int p = atomicAdd(&wpos[d], 1);
        col[p] = srcp[e];
    }
}

// ---------------- GEMM: [N x 128] @ [128 x 128], f32 vector ALU ----------------
// TRANS   : apply BN(from raw sums)+ReLU to A on load
// SPLIT   : W/bias staged from two 128x64 sources (Wmu|Wls, bmu|bls); cols 0..63 -> out, 64..127 -> out2
// RSCALE  : multiply output row by dinv[row]
// SLICEDIN: A is sliced (8 planes of [NN][16]); else row-major [NN][128]
// (!SPLIT output is sliced layout)

template<bool TRANS, bool SPLIT, bool RSCALE, bool SLICEDIN>
__global__ __launch_bounds__(256) void gemm_kernel(
    const float* __restrict__ A, const float* __restrict__ W, const float* __restrict__ Wb,
    const float* __restrict__ sums, const float* __restrict__ gamma, const float* __restrict__ beta,
    const float* __restrict__ bias, const float* __restrict__ bias2, const float* __restrict__ dinv,
    float* __restrict__ out, float* __restrict__ out2)
{
    __shared__ float Ws[64][128];    // 32 KB (one k-half of W)
    __shared__ float xT[128][36];    // 18 KB (transposed 32-row tile, padded)
    int tid = threadIdx.x;
    int row0 = blockIdx.x * 32;

    #pragma unroll
    for (int i = 0; i < 4; ++i) {           // stage 32x128 input tile (float4), transposed
        int idx = tid + i * 256;            // float4 index 0..1023
        int r = idx >> 5;                   // 32 float4 per row
        int k4 = (idx & 31) * 4;
        int gr = row0 + r;
        float vv[4] = {0.f, 0.f, 0.f, 0.f};
        if (gr < NN) {
            float4 v;
            if (SLICEDIN) v = *(const float4*)&A[(size_t)(k4 >> 4) * PLANE + (size_t)gr * 16 + (k4 & 15)];
            else          v = *(const float4*)&A[(size_t)gr * C + k4];
            vv[0] = v.x; vv[1] = v.y; vv[2] = v.z; vv[3] = v.w;
        }
        if (TRANS) {
            #pragma unroll
            for (int j = 0; j < 4; ++j) {
                int k = k4 + j;
                float mean = sums[k] * INVN;
                float var = fmaf(-mean, mean, sums[128 + k] * INVN);
                float sc = gamma[k] * rsqrtf(var + BN_EPS);
                float sh = fmaf(-mean, sc, beta[k]);
                vv[j] = fmaxf(fmaf(vv[j], sc, sh), 0.f);
            }
        }
        xT[k4 + 0][r] = vv[0]; xT[k4 + 1][r] = vv[1]; xT[k4 + 2][r] = vv[2]; xT[k4 + 3][r] = vv[3];
    }

    float acc[4][4] = {};
    int cg = (tid & 31) * 4;   // output col base
    int rg = (tid >> 5) * 4;   // local row base

    for (int kh = 0; kh < 2; ++kh) {
        __syncthreads();
        #pragma unroll
        for (int i = 0; i < 8; ++i) {       // stage W k-half
            int fi = tid + i * 256;         // float4 index 0..2047
            int k = fi >> 5;
            int c4 = (fi & 31) * 4;
            float4 wv;
            if (!SPLIT) wv = *(const float4*)&W[(size_t)(kh * 64 + k) * C + c4];
            else        wv = (c4 < 64) ? *(const float4*)&W[(size_t)(kh * 64 + k) * 64 + c4]
                                       : *(const float4*)&Wb[(size_t)(kh * 64 + k) * 64 + (c4 - 64)];
            *(float4*)&Ws[k][c4] = wv;
        }
        __syncthreads();
        #pragma unroll 8
        for (int k = 0; k < 64; ++k) {
            float4 a = *(const float4*)&xT[kh * 64 + k][rg];
            float4 b = *(const float4*)&Ws[k][cg];
            acc[0][0] = fmaf(a.x, b.x, acc[0][0]); acc[0][1] = fmaf(a.x, b.y, acc[0][1]);
            acc[0][2] = fmaf(a.x, b.z, acc[0][2]); acc[0][3] = fmaf(a.x, b.w, acc[0][3]);
            acc[1][0] = fmaf(a.y, b.x, acc[1][0]); acc[1][1] = fmaf(a.y, b.y, acc[1][1]);
            acc[1][2] = fmaf(a.y, b.z, acc[1][2]); acc[1][3] = fmaf(a.y, b.w, acc[1][3]);
            acc[2][0] = fmaf(a.z, b.x, acc[2][0]); acc[2][1] = fmaf(a.z, b.y, acc[2][1]);
            acc[2][2] = fmaf(a.z, b.z, acc[2][2]); acc[2][3] = fmaf(a.z, b.w, acc[2][3]);
            acc[3][0] = fmaf(a.w, b.x, acc[3][0]); acc[3][1] = fmaf(a.w, b.y, acc[3][1]);
            acc[3][2] = fmaf(a.w, b.z, acc[3][2]); acc[3][3] = fmaf(a.w, b.w, acc[3][3]);
        }
    }

    #pragma unroll
    for (int i = 0; i < 4; ++i) {
        int row = row0 + rg + i;
        if (row < NN) {
            float rs = RSCALE ? dinv[row] : 1.f;
            if (!SPLIT) {
                float4 o = make_float4(acc[i][0] * rs, acc[i][1] * rs, acc[i][2] * rs, acc[i][3] * rs);
                *(float4*)&out[(size_t)(cg >> 4) * PLANE + (size_t)row * 16 + (cg & 15)] = o;   // sliced
            } else {
                float* dst = (cg < 64) ? out : out2;
                int cc = cg & 63;
                float4 bq = (cg < 64) ? *(const float4*)&bias[cg] : *(const float4*)&bias2[cg - 64];
                float4 o = make_float4(acc[i][0] + bq.x, acc[i][1] + bq.y,
                                       acc[i][2] + bq.z, acc[i][3] + bq.w);
                *(float4*)&dst[(size_t)row * 64 + cc] = o;
            }
        }
    }
}

// ---------------- Sliced pull aggregation, float4 lanes ----------------
// Block b: slice g = b&7 (-> XCD round-robin), 8 rows (4 waves x 2 rows/wave).
// Half-wave (32 lanes) per row: sub = 8 edge chains, q4 = channel quad (float4).
// One gather instr = 16 edge-slices x 64B = 1KB. shfl_xor 4/8/16 reduce.
// !TRANS: input pre-scaled by dinv (RSCALE gemm): out = dinv[i]*(t'[i] + sum t'[s])
//  TRANS: input raw; f(v) = dinv[s]*relu(BN(v)) applied per gathered element (fused layer-3)

template<bool TRANS>
__global__ __launch_bounds__(256) void agg_kernel(
    const float* __restrict__ t, const int* __restrict__ rowptr, const int* __restrict__ col,
    const float* __restrict__ dinv,
    const float* __restrict__ sums, const float* __restrict__ gamma, const float* __restrict__ beta,
    float* __restrict__ outb)
{
    int g = blockIdx.x & 7;
    int rb = blockIdx.x >> 3;
    int wave = threadIdx.x >> 6;
    int lane = threadIdx.x & 63;
    int rsel = lane >> 5;           // which of the 2 rows in this wave
    int hl = lane & 31;
    int sub = hl >> 2;              // 8 edge chains
    int q4 = (hl & 3) * 4;          // channel quad within the 16-wide slice
    int row = rb * 8 + wave * 2 + rsel;   // NN = 50000 divisible by 8: no guard

    const float* tp = t + (size_t)g * PLANE + q4;

    float sc[4], sh[4];
    if (TRANS) {
        #pragma unroll
        for (int j = 0; j < 4; ++j) {
            int ch = g * 16 + q4 + j;
            float mean = sums[ch] * INVN;
            float var = fmaf(-mean, mean, sums[128 + ch] * INVN);
            sc[j] = gamma[ch] * rsqrtf(var + BN_EPS);
            sh[j] = fmaf(-mean, sc[j], beta[ch]);
        }
    }

    int e0 = rowptr[row], e1 = rowptr[row + 1];
    float a0 = 0.f, a1 = 0.f, a2 = 0.f, a3 = 0.f;

    int e = e0 + sub;
    for (; e + 8 < e1; e += 16) {       // 2 gathers in flight per lane
        int s0 = col[e], s1 = col[e + 8];
        float4 v0 = *(const float4*)&tp[(size_t)s0 * 16];
        float4 v1 = *(const float4*)&tp[(size_t)s1 * 16];
        if (TRANS) {
            float d0 = dinv[s0], d1 = dinv[s1];
            v0.x = d0 * fmaxf(fmaf(v0.x, sc[0], sh[0]), 0.f);
            v0.y = d0 * fmaxf(fmaf(v0.y, sc[1], sh[1]), 0.f);
            v0.z = d0 * fmaxf(fmaf(v0.z, sc[2], sh[2]), 0.f);
            v0.w = d0 * fmaxf(fmaf(v0.w, sc[3], sh[3]), 0.f);
            v1.x = d1 * fmaxf(fmaf(v1.x, sc[0], sh[0]), 0.f);
            v1.y = d1 * fmaxf(fmaf(v1.y, sc[1], sh[1]), 0.f);
            v1.z = d1 * fmaxf(fmaf(v1.z, sc[2], sh[2]), 0.f);
            v1.w = d1 * fmaxf(fmaf(v1.w, sc[3], sh[3]), 0.f);
        }
        a0 += v0.x + v1.x; a1 += v0.y + v1.y; a2 += v0.z + v1.z; a3 += v0.w + v1.w;
    }
    if (e < e1) {                        // <=1 remaining step per chain
        int s = col[e];
        float4 v = *(const float4*)&tp[(size_t)s * 16];
        if (TRANS) {
            float d = dinv[s];
            v.x = d * fmaxf(fmaf(v.x, sc[0], sh[0]), 0.f);
            v.y = d * fmaxf(fmaf(v.y, sc[1], sh[1]), 0.f);
            v.z = d * fmaxf(fmaf(v.z, sc[2], sh[2]), 0.f);
            v.w = d * fmaxf(fmaf(v.w, sc[3], sh[3]), 0.f);
        }
        a0 += v.x; a1 += v.y; a2 += v.z; a3 += v.w;
    }

    #pragma unroll
    for (int st = 4; st <= 16; st <<= 1) {   // reduce across 8 chains (lane bits 2..4)
        a0 += __shfl_xor(a0, st);
        a1 += __shfl_xor(a1, st);
        a2 += __shfl_xor(a2, st);
        a3 += __shfl_xor(a3, st);
    }

    if (sub == 0) {
        float di = dinv[row];
        float4 v = *(const float4*)&tp[(size_t)row * 16];    // self-loop
        if (TRANS) {
            v.x = di * fmaxf(fmaf(v.x, sc[0], sh[0]), 0.f);
            v.y = di * fmaxf(fmaf(v.y, sc[1], sh[1]), 0.f);
            v.z = di * fmaxf(fmaf(v.z, sc[2], sh[2]), 0.f);
            v.w = di * fmaxf(fmaf(v.w, sc[3], sh[3]), 0.f);
        }
        a0 += v.x; a1 += v.y; a2 += v.z; a3 += v.w;
        float4 o = make_float4(di * a0, di * a1, di * a2, di * a3);
        *(float4*)&outb[(size_t)g * PLANE + (size_t)row * 16 + q4] = o;
    }
}

// ---------------- BatchNorm stats (sliced input) ----------------

__global__ __launch_bounds__(256) void bnstats_kernel(const float* __restrict__ h, float* __restrict__ sums) {
    int c = threadIdx.x & 127;
    int hh = threadIdx.x >> 7;
    const float* hp = h + (size_t)(c >> 4) * PLANE + (c & 15);
    float s = 0.f, sq = 0.f;
    for (int r = blockIdx.x * 2 + hh; r < NN; r += gridDim.x * 2) {
        float v = hp[(size_t)r * 16];
        s += v; sq = fmaf(v, v, sq);
    }
    __shared__ float ls[256], lq[256];
    ls[threadIdx.x] = s; lq[threadIdx.x] = sq;
    __syncthreads();
    if (hh == 0) {
        atomicAdd(&sums[c], s + ls[c + 128]);
        atomicAdd(&sums[128 + c], sq + lq[c + 128]);
    }
}

// ---------------- launch ----------------

extern "C" void kernel_launch(void* const* d_in, const int* in_sizes, int n_in,
                              void* d_out, int out_size, void* d_ws, size_t ws_size,
                              hipStream_t stream) {
    (void)in_sizes; (void)n_in; (void)out_size; (void)ws_size;
    const float* x      = (const float*)d_in[0];
    const int*   ei     = (const int*)d_in[1];
    const float* W1     = (const float*)d_in[2];
    // d_in[3] = b1: cancelled exactly by BN mean-subtraction
    const float* gamma1 = (const float*)d_in[4];
    const float* beta1  = (const float*)d_in[5];
    const float* W2     = (const float*)d_in[6];
    // d_in[7] = b2: cancelled exactly by BN
    const float* gamma2 = (const float*)d_in[8];
    const float* beta2  = (const float*)d_in[9];
    const float* Wmu    = (const float*)d_in[10];
    const float* bmu    = (const float*)d_in[11];
    const float* Wls    = (const float*)d_in[12];
    const float* bls    = (const float*)d_in[13];

    float* outmu = (float*)d_out;
    float* outls = outmu + (size_t)NN * OUTC;

    char* w = (char*)d_ws;
    size_t off = 0;
    auto alloc = [&](size_t bytes) { char* p = w + off; off = (off + bytes + 255) & ~(size_t)255; return p; };
    float* t      = (float*)alloc(sizeof(float) * NN * C);       // 25.6 MB (sliced)
    float* aggb   = (float*)alloc(sizeof(float) * NN * C);       // 25.6 MB (sliced)
    int*   cnt    = (int*)  alloc(sizeof(int) * NN);
    float* sums   = (float*)alloc(sizeof(float) * 512);          // adjacent to cnt: one memset covers both
    int*   rowptr = (int*)  alloc(sizeof(int) * (NN + 1));
    int*   wpos   = (int*)  alloc(sizeof(int) * NN);
    int*   col    = (int*)  alloc(sizeof(int) * NE);
    float* dinv   = (float*)alloc(sizeof(float) * NN);
    int*   bsum   = (int*)  alloc(sizeof(int) * 64);
    float* sumsA = sums; float* sumsB = sums + 256;

    const int* srcp = ei;
    const int* dstp = ei + NE;

    size_t zspan = (size_t)((char*)(sums + 512) - (char*)cnt);
    hipMemsetAsync(cnt, 0, zspan, stream);

    hist_kernel<<<(NE + 255) / 256, 256, 0, stream>>>(dstp, cnt);
    scan1_kernel<<<NBLK, 256, 0, stream>>>(cnt, rowptr, dinv, bsum);
    scan3_kernel<<<NBLK, 256, 0, stream>>>(bsum, rowptr, wpos);
    fill_kernel<<<(NE + 255) / 256, 256, 0, stream>>>(srcp, dstp, wpos, col);

    const int GB = (NN + 31) / 32;
    const int AB = (NN / 8) * 8;        // 6250 row-blocks x 8 slices

    // layer 1: t = dinv .* (x@W1) [sliced] ; aggb = aggregate ; BN1 stats
    gemm_kernel<false, false, true, false><<<GB, 256, 0, stream>>>(x, W1, nullptr, nullptr, nullptr, nullptr, nullptr, nullptr, dinv, t, nullptr);
    agg_kernel<false><<<AB, 256, 0, stream>>>(t, rowptr, col, dinv, nullptr, nullptr, nullptr, aggb);
    bnstats_kernel<<<400, 256, 0, stream>>>(aggb, sumsA);

    // layer 2: t = dinv .* (relu(BN1(aggb))@W2) [sliced] ; aggb = aggregate ; BN2 stats
    gemm_kernel<true, false, true, true><<<GB, 256, 0, stream>>>(aggb, W2, nullptr, sumsA, gamma1, beta1, nullptr, nullptr, dinv, t, nullptr);
    agg_kernel<false><<<AB, 256, 0, stream>>>(t, rowptr, col, dinv, nullptr, nullptr, nullptr, aggb);
    bnstats_kernel<<<400, 256, 0, stream>>>(aggb, sumsB);

    // heads: t = aggregate(dinv .* relu(BN2(aggb))) [fused] ; [mu|ls] = t @ [Wmu|Wls] + [bmu|bls]
    agg_kernel<true><<<AB, 256, 0, stream>>>(aggb, rowptr, col, dinv, sumsB, gamma2, beta2, t);
    gemm_kernel<false, true, false, true><<<GB, 256, 0, stream>>>(t, Wmu, Wls, nullptr, nullptr, nullptr, bmu, bls, nullptr, outmu, outls);
}

// Round 5
// 448.413 us; speedup vs baseline: 1.5931x; 1.2229x over previous
//
#include <hip/hip_runtime.h>

#define NN 50000
#define NE 800000
#define C 128
#define OUTC 64
#define BN_EPS 1e-5f
#define INVN (1.0f / 50000.0f)
#define NBLK 49   // ceil(NN/1024)

// round-to-nearest-even f32 -> bf16 (finite values)
__device__ __forceinline__ unsigned short f2bf(float f) {
    unsigned u = __float_as_uint(f);
    u += 0x7fffu + ((u >> 16) & 1u);
    return (unsigned short)(u >> 16);
}

// ---------------- CSR build ----------------

__global__ __launch_bounds__(256) void hist_kernel(const int* __restrict__ dstp, int* __restrict__ cnt) {
    int e = blockIdx.x * 256 + threadIdx.x;
    if (e < NE) atomicAdd(&cnt[dstp[e]], 1);
}

__global__ __launch_bounds__(256) void scan1_kernel(const int* __restrict__ cnt, int* __restrict__ rowptr,
                                                    float* __restrict__ dinv, int* __restrict__ bsum) {
    __shared__ int lds[256];
    int tid = threadIdx.x;
    int base = blockIdx.x * 1024 + tid * 4;
    int v[4];
    int s = 0;
    #pragma unroll
    for (int j = 0; j < 4; ++j) { int i = base + j; v[j] = (i < NN) ? cnt[i] : 0; s += v[j]; }
    lds[tid] = s;
    __syncthreads();
    for (int off = 1; off < 256; off <<= 1) {
        int x = (tid >= off) ? lds[tid - off] : 0;
        __syncthreads();
        lds[tid] += x;
        __syncthreads();
    }
    int excl = lds[tid] - s;
    #pragma unroll
    for (int j = 0; j < 4; ++j) {
        int i = base + j;
        if (i < NN) {
            rowptr[i] = excl;                       // local exclusive; block offset added in scan3
            dinv[i] = rsqrtf((float)(v[j] + 1));    // +1 self-loop
        }
        excl += v[j];
    }
    if (tid == 255) bsum[blockIdx.x] = lds[255];
}

// adds block offsets (inline 49-element scan of bsum), mirrors into wpos
__global__ __launch_bounds__(256) void scan3_kernel(const int* __restrict__ bsum, int* __restrict__ rowptr,
                                                    int* __restrict__ wpos) {
    __shared__ int boff;
    int tid = threadIdx.x;
    if (tid < 64) {
        int orig = (tid < NBLK) ? bsum[tid] : 0;
        int v = orig;
        #pragma unroll
        for (int off = 1; off < 64; off <<= 1) {
            int x = __shfl_up(v, off);
            if (tid >= off) v += x;
        }
        if (tid == (int)blockIdx.x) boff = v - orig;   // exclusive prefix at this block
    }
    __syncthreads();
    int off = boff;
    int base = blockIdx.x * 1024 + tid * 4;
    #pragma unroll
    for (int j = 0; j < 4; ++j) {
        int i = base + j;
        if (i < NN) { int r = rowptr[i] + off; rowptr[i] = r; wpos[i] = r; }
    }
    if (blockIdx.x == 0 && tid == 0) rowptr[NN] = NE;
}

__global__ __launch_bounds__(256) void fill_kernel(const int* __restrict__ srcp, const int* __restrict__ dstp,
                                                   int* __restrict__ wpos, int* __restrict__ col) {
    int e = blockIdx.x * 256 + threadIdx.x;
    if (e < NE) {
        int d = dstp[e];
        int p = atomicAdd(&wpos[d], 1);
        col[p] = srcp[e];
    }
}

// ---------------- GEMM: [N x 128] @ [128 x 128], f32 compute, bf16 output ----------------
// TRANS : apply BN(from raw sums)+ReLU to A on load
// SPLITW: stage W from two 128x64 sources (Wmu|Wls)
// Output: t[row][c] = bf16( dinv[row] * acc )   (pre-scaled for pure-sum aggregation)

template<bool TRANS, bool SPLITW>
__global__ __launch_bounds__(256) void gemm_kernel(
    const float* __restrict__ A, const float* __restrict__ W, const float* __restrict__ Wb,
    const float* __restrict__ sums, const float* __restrict__ gamma, const float* __restrict__ beta,
    const float* __restrict__ dinv, unsigned short* __restrict__ out)
{
    __shared__ float Ws[64][128];    // 32 KB (one k-half of W)
    __shared__ float xT[128][36];    // 18 KB (transposed 32-row tile, padded)
    int tid = threadIdx.x;
    int row0 = blockIdx.x * 32;

    #pragma unroll
    for (int i = 0; i < 4; ++i) {           // stage 32x128 input tile (float4), transposed
        int idx = tid + i * 256;            // float4 index 0..1023
        int r = idx >> 5;                   // 32 float4 per row
        int k4 = (idx & 31) * 4;
        int gr = row0 + r;
        float vv[4] = {0.f, 0.f, 0.f, 0.f};
        if (gr < NN) {
            float4 v = *(const float4*)&A[(size_t)gr * C + k4];
            vv[0] = v.x; vv[1] = v.y; vv[2] = v.z; vv[3] = v.w;
        }
        if (TRANS) {
            #pragma unroll
            for (int j = 0; j < 4; ++j) {
                int k = k4 + j;
                float mean = sums[k] * INVN;
                float var = fmaf(-mean, mean, sums[128 + k] * INVN);
                float sc = gamma[k] * rsqrtf(var + BN_EPS);
                float sh = fmaf(-mean, sc, beta[k]);
                vv[j] = fmaxf(fmaf(vv[j], sc, sh), 0.f);
            }
        }
        xT[k4 + 0][r] = vv[0]; xT[k4 + 1][r] = vv[1]; xT[k4 + 2][r] = vv[2]; xT[k4 + 3][r] = vv[3];
    }

    float acc[4][4] = {};
    int cg = (tid & 31) * 4;   // output col base
    int rg = (tid >> 5) * 4;   // local row base

    for (int kh = 0; kh < 2; ++kh) {
        __syncthreads();
        #pragma unroll
        for (int i = 0; i < 8; ++i) {       // stage W k-half
            int fi = tid + i * 256;         // float4 index 0..2047
            int k = fi >> 5;
            int c4 = (fi & 31) * 4;
            float4 wv;
            if (!SPLITW) wv = *(const float4*)&W[(size_t)(kh * 64 + k) * C + c4];
            else         wv = (c4 < 64) ? *(const float4*)&W[(size_t)(kh * 64 + k) * 64 + c4]
                                        : *(const float4*)&Wb[(size_t)(kh * 64 + k) * 64 + (c4 - 64)];
            *(float4*)&Ws[k][c4] = wv;
        }
        __syncthreads();
        #pragma unroll 8
        for (int k = 0; k < 64; ++k) {
            float4 a = *(const float4*)&xT[kh * 64 + k][rg];
            float4 b = *(const float4*)&Ws[k][cg];
            acc[0][0] = fmaf(a.x, b.x, acc[0][0]); acc[0][1] = fmaf(a.x, b.y, acc[0][1]);
            acc[0][2] = fmaf(a.x, b.z, acc[0][2]); acc[0][3] = fmaf(a.x, b.w, acc[0][3]);
            acc[1][0] = fmaf(a.y, b.x, acc[1][0]); acc[1][1] = fmaf(a.y, b.y, acc[1][1]);
            acc[1][2] = fmaf(a.y, b.z, acc[1][2]); acc[1][3] = fmaf(a.y, b.w, acc[1][3]);
            acc[2][0] = fmaf(a.z, b.x, acc[2][0]); acc[2][1] = fmaf(a.z, b.y, acc[2][1]);
            acc[2][2] = fmaf(a.z, b.z, acc[2][2]); acc[2][3] = fmaf(a.z, b.w, acc[2][3]);
            acc[3][0] = fmaf(a.w, b.x, acc[3][0]); acc[3][1] = fmaf(a.w, b.y, acc[3][1]);
            acc[3][2] = fmaf(a.w, b.z, acc[3][2]); acc[3][3] = fmaf(a.w, b.w, acc[3][3]);
        }
    }

    #pragma unroll
    for (int i = 0; i < 4; ++i) {
        int row = row0 + rg + i;
        if (row < NN) {
            float rs = dinv[row];
            ushort4 o;
            o.x = f2bf(acc[i][0] * rs); o.y = f2bf(acc[i][1] * rs);
            o.z = f2bf(acc[i][2] * rs); o.w = f2bf(acc[i][3] * rs);
            *(ushort4*)&out[(size_t)row * C + cg] = o;   // 8B aligned (cg % 4 == 0)
        }
    }
}

// ---------------- Pull aggregation from bf16 table (pure gather-sum) ----------------
// t rows pre-scaled by dinv: out[i] = dinv[i] * ( t'[i] + sum_e t'[col[e]] )
// One wave per row, lane covers channels 2l, 2l+1 (one dword load per edge = 256B/row/instr).
// !SPLIT: write f32 row [NN][128].  SPLIT: final heads - split 64|64 + bias.

template<bool SPLIT>
__global__ __launch_bounds__(256) void agg_kernel(
    const unsigned short* __restrict__ t, const int* __restrict__ rowptr, const int* __restrict__ col,
    const float* __restrict__ dinv, const float* __restrict__ bmu, const float* __restrict__ bls,
    float* __restrict__ outb, float* __restrict__ out2)
{
    int wave = threadIdx.x >> 6;
    int lane = threadIdx.x & 63;
    int row = blockIdx.x * 4 + wave;     // NN % 4 == 0: no guard
    int c = lane * 2;
    const unsigned short* tp = t + c;
    float di = dinv[row];
    int e0 = rowptr[row], e1 = rowptr[row + 1];

    unsigned vs = *(const unsigned*)&tp[(size_t)row * C];          // self-loop
    float a0 = __uint_as_float(vs << 16);
    float a1 = __uint_as_float(vs & 0xffff0000u);

    int e = e0;
    for (; e + 3 < e1; e += 4) {          // 4 independent gather chains
        int s0 = col[e], s1 = col[e + 1], s2 = col[e + 2], s3 = col[e + 3];
        unsigned v0 = *(const unsigned*)&tp[(size_t)s0 * C];
        unsigned v1 = *(const unsigned*)&tp[(size_t)s1 * C];
        unsigned v2 = *(const unsigned*)&tp[(size_t)s2 * C];
        unsigned v3 = *(const unsigned*)&tp[(size_t)s3 * C];
        a0 += (__uint_as_float(v0 << 16) + __uint_as_float(v1 << 16))
            + (__uint_as_float(v2 << 16) + __uint_as_float(v3 << 16));
        a1 += (__uint_as_float(v0 & 0xffff0000u) + __uint_as_float(v1 & 0xffff0000u))
            + (__uint_as_float(v2 & 0xffff0000u) + __uint_as_float(v3 & 0xffff0000u));
    }
    for (; e < e1; ++e) {
        int s = col[e];
        unsigned v = *(const unsigned*)&tp[(size_t)s * C];
        a0 += __uint_as_float(v << 16);
        a1 += __uint_as_float(v & 0xffff0000u);
    }

    if (!SPLIT) {
        *(float2*)&outb[(size_t)row * C + c] = make_float2(di * a0, di * a1);
    } else {
        if (c < 64) *(float2*)&outb[(size_t)row * OUTC + c]
                        = make_float2(fmaf(di, a0, bmu[c]), fmaf(di, a1, bmu[c + 1]));
        else        *(float2*)&out2[(size_t)row * OUTC + (c - 64)]
                        = make_float2(fmaf(di, a0, bls[c - 64]), fmaf(di, a1, bls[c - 63]));
    }
}

// ---------------- BatchNorm stats (f32 row-major input) ----------------

__global__ __launch_bounds__(256) void bnstats_kernel(const float* __restrict__ h, float* __restrict__ sums) {
    int c = threadIdx.x & 127;
    int hh = threadIdx.x >> 7;
    float s = 0.f, sq = 0.f;
    for (int r = blockIdx.x * 2 + hh; r < NN; r += gridDim.x * 2) {
        float v = h[(size_t)r * C + c];
        s += v; sq = fmaf(v, v, sq);
    }
    __shared__ float ls[256], lq[256];
    ls[threadIdx.x] = s; lq[threadIdx.x] = sq;
    __syncthreads();
    if (hh == 0) {
        atomicAdd(&sums[c], s + ls[c + 128]);
        atomicAdd(&sums[128 + c], sq + lq[c + 128]);
    }
}

// ---------------- launch ----------------

extern "C" void kernel_launch(void* const* d_in, const int* in_sizes, int n_in,
                              void* d_out, int out_size, void* d_ws, size_t ws_size,
                              hipStream_t stream) {
    (void)in_sizes; (void)n_in; (void)out_size; (void)ws_size;
    const float* x      = (const float*)d_in[0];
    const int*   ei     = (const int*)d_in[1];
    const float* W1     = (const float*)d_in[2];
    // d_in[3] = b1: cancelled exactly by BN mean-subtraction
    const float* gamma1 = (const float*)d_in[4];
    const float* beta1  = (const float*)d_in[5];
    const float* W2     = (const float*)d_in[6];
    // d_in[7] = b2: cancelled exactly by BN
    const float* gamma2 = (const float*)d_in[8];
    const float* beta2  = (const float*)d_in[9];
    const float* Wmu    = (const float*)d_in[10];
    const float* bmu    = (const float*)d_in[11];
    const float* Wls    = (const float*)d_in[12];
    const float* bls    = (const float*)d_in[13];

    float* outmu = (float*)d_out;
    float* outls = outmu + (size_t)NN * OUTC;

    char* w = (char*)d_ws;
    size_t off = 0;
    auto alloc = [&](size_t bytes) { char* p = w + off; off = (off + bytes + 255) & ~(size_t)255; return p; };
    unsigned short* t = (unsigned short*)alloc(sizeof(unsigned short) * NN * C);  // 12.8 MB bf16
    float* aggb   = (float*)alloc(sizeof(float) * NN * C);       // 25.6 MB f32
    int*   cnt    = (int*)  alloc(sizeof(int) * NN);
    float* sums   = (float*)alloc(sizeof(float) * 512);          // adjacent to cnt: one memset covers both
    int*   rowptr = (int*)  alloc(sizeof(int) * (NN + 1));
    int*   wpos   = (int*)  alloc(sizeof(int) * NN);
    int*   col    = (int*)  alloc(sizeof(int) * NE);
    float* dinv   = (float*)alloc(sizeof(float) * NN);
    int*   bsum   = (int*)  alloc(sizeof(int) * 64);
    float* sumsA = sums; float* sumsB = sums + 256;

    const int* srcp = ei;
    const int* dstp = ei + NE;

    size_t zspan = (size_t)((char*)(sums + 512) - (char*)cnt);
    hipMemsetAsync(cnt, 0, zspan, stream);

    hist_kernel<<<(NE + 255) / 256, 256, 0, stream>>>(dstp, cnt);
    scan1_kernel<<<NBLK, 256, 0, stream>>>(cnt, rowptr, dinv, bsum);
    scan3_kernel<<<NBLK, 256, 0, stream>>>(bsum, rowptr, wpos);
    fill_kernel<<<(NE + 255) / 256, 256, 0, stream>>>(srcp, dstp, wpos, col);

    const int GB = (NN + 31) / 32;
    const int AB = NN / 4;

    // layer 1: t = bf16(dinv .* (x@W1)) ; aggb = aggregate ; BN1 stats
    gemm_kernel<false, false><<<GB, 256, 0, stream>>>(x, W1, nullptr, nullptr, nullptr, nullptr, dinv, t);
    agg_kernel<false><<<AB, 256, 0, stream>>>(t, rowptr, col, dinv, nullptr, nullptr, aggb, nullptr);
    bnstats_kernel<<<400, 256, 0, stream>>>(aggb, sumsA);

    // layer 2: t = bf16(dinv .* (relu(BN1(aggb))@W2)) ; aggb = aggregate ; BN2 stats
    gemm_kernel<true, false><<<GB, 256, 0, stream>>>(aggb, W2, nullptr, sumsA, gamma1, beta1, dinv, t);
    agg_kernel<false><<<AB, 256, 0, stream>>>(t, rowptr, col, dinv, nullptr, nullptr, aggb, nullptr);
    bnstats_kernel<<<400, 256, 0, stream>>>(aggb, sumsB);

    // heads (reassociated): t = bf16(dinv .* (relu(BN2(aggb)) @ [Wmu|Wls])) ; agg3 -> split + bias
    gemm_kernel<true, true><<<GB, 256, 0, stream>>>(aggb, Wmu, Wls, sumsB, gamma2, beta2, dinv, t);
    agg_kernel<true><<<AB, 256, 0, stream>>>(t, rowptr, col, dinv, bmu, bls, outmu, outls);
}

// Round 6
// 408.075 us; speedup vs baseline: 1.7505x; 1.0989x over previous
//
#include <hip/hip_runtime.h>

#define NN 50000
#define NE 800000
#define C 128
#define OUTC 64
#define BN_EPS 1e-5f
#define INVN (1.0f / 50000.0f)
#define NBLK 49   // ceil(NN/1024)

typedef __attribute__((ext_vector_type(8))) short bf16x8;
typedef __attribute__((ext_vector_type(4))) float f32x4;
typedef __attribute__((ext_vector_type(8))) unsigned short u16x8;

// round-to-nearest-even f32 -> bf16 (finite values)
__device__ __forceinline__ unsigned short f2bf(float f) {
    unsigned u = __float_as_uint(f);
    u += 0x7fffu + ((u >> 16) & 1u);
    return (unsigned short)(u >> 16);
}
__device__ __forceinline__ float bf2f(unsigned short s) {
    return __uint_as_float((unsigned)s << 16);
}

// ---------------- CSR build ----------------

__global__ __launch_bounds__(256) void hist_kernel(const int* __restrict__ dstp, int* __restrict__ cnt) {
    int e = blockIdx.x * 256 + threadIdx.x;
    if (e < NE) atomicAdd(&cnt[dstp[e]], 1);
}

__global__ __launch_bounds__(256) void scan1_kernel(const int* __restrict__ cnt, int* __restrict__ rowptr,
                                                    float* __restrict__ dinv, int* __restrict__ bsum) {
    __shared__ int lds[256];
    int tid = threadIdx.x;
    int base = blockIdx.x * 1024 + tid * 4;
    int v[4];
    int s = 0;
    #pragma unroll
    for (int j = 0; j < 4; ++j) { int i = base + j; v[j] = (i < NN) ? cnt[i] : 0; s += v[j]; }
    lds[tid] = s;
    __syncthreads();
    for (int off = 1; off < 256; off <<= 1) {
        int x = (tid >= off) ? lds[tid - off] : 0;
        __syncthreads();
        lds[tid] += x;
        __syncthreads();
    }
    int excl = lds[tid] - s;
    #pragma unroll
    for (int j = 0; j < 4; ++j) {
        int i = base + j;
        if (i < NN) {
            rowptr[i] = excl;                       // local exclusive; block offset added in scan3
            dinv[i] = rsqrtf((float)(v[j] + 1));    // +1 self-loop
        }
        excl += v[j];
    }
    if (tid == 255) bsum[blockIdx.x] = lds[255];
}

// adds block offsets (inline 49-element scan of bsum), mirrors into wpos
__global__ __launch_bounds__(256) void scan3_kernel(const int* __restrict__ bsum, int* __restrict__ rowptr,
                                                    int* __restrict__ wpos) {
    __shared__ int boff;
    int tid = threadIdx.x;
    if (tid < 64) {
        int orig = (tid < NBLK) ? bsum[tid] : 0;
        int v = orig;
        #pragma unroll
        for (int off = 1; off < 64; off <<= 1) {
            int x = __shfl_up(v, off);
            if (tid >= off) v += x;
        }
        if (tid == (int)blockIdx.x) boff = v - orig;   // exclusive prefix at this block
    }
    __syncthreads();
    int off = boff;
    int base = blockIdx.x * 1024 + tid * 4;
    #pragma unroll
    for (int j = 0; j < 4; ++j) {
        int i = base + j;
        if (i < NN) { int r = rowptr[i] + off; rowptr[i] = r; wpos[i] = r; }
    }
    if (blockIdx.x == 0 && tid == 0) rowptr[NN] = NE;
}

__global__ __launch_bounds__(256) void fill_kernel(const int* __restrict__ srcp, const int* __restrict__ dstp,
                                                   int* __restrict__ wpos, int* __restrict__ col) {
    int e = blockIdx.x * 256 + threadIdx.x;
    if (e < NE) {
        int d = dstp[e];
        int p = atomicAdd(&wpos[d], 1);
        col[p] = srcp[e];
    }
}

// ---------------- W pre-pack: bf16, MFMA B-fragment layout ----------------
// Wpk[mat][kt(4)][nt(8)][lane(64)][8 bf16]: lane holds W[kt*32 + (lane>>4)*8 + j][nt*16 + (lane&15)]
// mat 0 = W1, 1 = W2, 2 = [Wmu|Wls]

__global__ __launch_bounds__(256) void prep_kernel(const float* __restrict__ W1, const float* __restrict__ W2,
                                                   const float* __restrict__ Wmu, const float* __restrict__ Wls,
                                                   unsigned short* __restrict__ Wpk) {
    int idx = blockIdx.x * 256 + threadIdx.x;    // 0..6143
    if (idx >= 3 * 2048) return;
    int which = idx >> 11;
    int r = idx & 2047;
    int l = r & 63;
    int nt = (r >> 6) & 7;
    int kt = r >> 9;
    int m = l & 15, kg = l >> 4;
    int c = nt * 16 + m;
    bf16x8 o;
    #pragma unroll
    for (int j = 0; j < 8; ++j) {
        int k = kt * 32 + kg * 8 + j;
        float w;
        if (which == 0)      w = W1[k * 128 + c];
        else if (which == 1) w = W2[k * 128 + c];
        else                 w = (c < 64) ? Wmu[k * 64 + c] : Wls[k * 64 + (c - 64)];
        o[j] = (short)f2bf(w);
    }
    *(bf16x8*)&Wpk[(size_t)which * 16384 + (size_t)r * 8] = o;
}

// ---------------- GEMM: [N x 128] @ [128 x 128] via bf16 MFMA, f32 accum ----------------
// TRANS: apply BN(from raw sums)+ReLU to A rows on load (f32), then cvt to bf16
// Output: t[row][c] = bf16(dinv[row] * acc)  (pre-scaled for pure-sum aggregation)
// Block: 32 rows, 4 waves = 2 row-halves x 2 col-halves. Wave: 16 rows x 64 cols.

template<bool TRANS>
__global__ __launch_bounds__(256) void gemm_kernel(
    const float* __restrict__ A, const unsigned short* __restrict__ Wpk,
    const float* __restrict__ sums, const float* __restrict__ gamma, const float* __restrict__ beta,
    const float* __restrict__ dinv, unsigned short* __restrict__ out)
{
    int tid = threadIdx.x;
    int wv = tid >> 6, l = tid & 63;
    int m = l & 15, kg = l >> 4;
    int rhalf = wv & 1, chalf = wv >> 1;
    int row = blockIdx.x * 32 + rhalf * 16 + m;
    int rowc = min(row, NN - 1);
    const float* Ar = A + (size_t)rowc * C;

    f32x4 acc[4] = {};

    #pragma unroll
    for (int kt = 0; kt < 4; ++kt) {
        int k0 = kt * 32 + kg * 8;
        float4 x0 = *(const float4*)&Ar[k0];
        float4 x1 = *(const float4*)&Ar[k0 + 4];
        float av[8] = {x0.x, x0.y, x0.z, x0.w, x1.x, x1.y, x1.z, x1.w};
        if (TRANS) {
            #pragma unroll
            for (int j = 0; j < 8; ++j) {
                int k = k0 + j;
                float mean = sums[k] * INVN;
                float var = fmaf(-mean, mean, sums[128 + k] * INVN);
                float sc = gamma[k] * rsqrtf(var + BN_EPS);
                float sh = fmaf(-mean, sc, beta[k]);
                av[j] = fmaxf(fmaf(av[j], sc, sh), 0.f);
            }
        }
        bf16x8 af;
        #pragma unroll
        for (int j = 0; j < 8; ++j) af[j] = (short)f2bf(av[j]);
        #pragma unroll
        for (int n = 0; n < 4; ++n) {
            int nt = chalf * 4 + n;
            bf16x8 bfr = *(const bf16x8*)&Wpk[(size_t)((kt * 8 + nt) * 64 + l) * 8];
            acc[n] = __builtin_amdgcn_mfma_f32_16x16x32_bf16(af, bfr, acc[n], 0, 0, 0);
        }
    }

    // D: lane l holds D[(l>>4)*4 + r][nt*16 + (l&15)]
    int ro = blockIdx.x * 32 + rhalf * 16 + kg * 4;
    #pragma unroll
    for (int r = 0; r < 4; ++r) {
        int orow = ro + r;
        if (orow < NN) {
            float di = dinv[orow];
            #pragma unroll
            for (int n = 0; n < 4; ++n)
                out[(size_t)orow * C + (chalf * 4 + n) * 16 + m] = f2bf(di * acc[n][r]);
        }
    }
}

// ---------------- Pull aggregation from bf16 table, 4 edges per gather instr ----------------
// Wave per row. lane = eg(=l>>4: edge slot) x q(=l&15: channel-8th, ch q*8..q*8+7).
// Per batch of 16 edges: 4 gathers of ushort8 (16B/lane, 1KB/instr = 4 edge-rows).
// Load phase separated from fma phase so 4 gathers are in flight.
// !SPLIT: out f32 [NN][128].  SPLIT: heads - split 64|64 + bias.

template<bool SPLIT>
__global__ __launch_bounds__(256) void agg_kernel(
    const unsigned short* __restrict__ t, const int* __restrict__ rowptr, const int* __restrict__ col,
    const float* __restrict__ dinv, const float* __restrict__ bmu, const float* __restrict__ bls,
    float* __restrict__ outb, float* __restrict__ out2)
{
    int wave = threadIdx.x >> 6, lane = threadIdx.x & 63;
    int row = blockIdx.x * 4 + wave;     // NN % 4 == 0: no guard
    int q = lane & 15, eg = lane >> 4;
    const unsigned short* tq = t + q * 8;
    int e0 = rowptr[row], e1 = rowptr[row + 1];
    float a[8] = {};

    for (int e = e0; e < e1; e += 16) {
        int lim = e1 - 1;
        u16x8 v[4];
        float msk[4];
        #pragma unroll
        for (int b = 0; b < 4; ++b) {
            int i = e + b * 4 + eg;
            msk[b] = (i < e1) ? 1.f : 0.f;
            if (e + b * 4 < e1) {                       // wave-uniform batch-live check
                int s = col[min(i, lim)];
                v[b] = *(const u16x8*)&tq[(size_t)s * C];
            } else {
                v[b] = (u16x8)0;
                msk[b] = 0.f;
            }
        }
        #pragma unroll
        for (int b = 0; b < 4; ++b) {
            #pragma unroll
            for (int j = 0; j < 8; ++j)
                a[j] = fmaf(msk[b], bf2f(v[b][j]), a[j]);
        }
    }

    {   // self-loop: counted once (eg==0 lanes only)
        u16x8 vs = *(const u16x8*)&tq[(size_t)row * C];
        float ms = (eg == 0) ? 1.f : 0.f;
        #pragma unroll
        for (int j = 0; j < 8; ++j)
            a[j] = fmaf(ms, bf2f(vs[j]), a[j]);
    }

    #pragma unroll
    for (int j = 0; j < 8; ++j) {
        a[j] += __shfl_xor(a[j], 16);
        a[j] += __shfl_xor(a[j], 32);
    }

    if (eg == 0) {
        float di = dinv[row];
        int c = q * 8;
        if (!SPLIT) {
            *(float4*)&outb[(size_t)row * C + c]     = make_float4(di*a[0], di*a[1], di*a[2], di*a[3]);
            *(float4*)&outb[(size_t)row * C + c + 4] = make_float4(di*a[4], di*a[5], di*a[6], di*a[7]);
        } else {
            if (c < 64) {
                float4 b0 = *(const float4*)&bmu[c];
                float4 b1 = *(const float4*)&bmu[c + 4];
                *(float4*)&outb[(size_t)row * OUTC + c]
                    = make_float4(fmaf(di,a[0],b0.x), fmaf(di,a[1],b0.y), fmaf(di,a[2],b0.z), fmaf(di,a[3],b0.w));
                *(float4*)&outb[(size_t)row * OUTC + c + 4]
                    = make_float4(fmaf(di,a[4],b1.x), fmaf(di,a[5],b1.y), fmaf(di,a[6],b1.z), fmaf(di,a[7],b1.w));
            } else {
                int cc = c - 64;
                float4 b0 = *(const float4*)&bls[cc];
                float4 b1 = *(const float4*)&bls[cc + 4];
                *(float4*)&out2[(size_t)row * OUTC + cc]
                    = make_float4(fmaf(di,a[0],b0.x), fmaf(di,a[1],b0.y), fmaf(di,a[2],b0.z), fmaf(di,a[3],b0.w));
                *(float4*)&out2[(size_t)row * OUTC + cc + 4]
                    = make_float4(fmaf(di,a[4],b1.x), fmaf(di,a[5],b1.y), fmaf(di,a[6],b1.z), fmaf(di,a[7],b1.w));
            }
        }
    }
}

// ---------------- BatchNorm stats (f32 row-major input) ----------------

__global__ __launch_bounds__(256) void bnstats_kernel(const float* __restrict__ h, float* __restrict__ sums) {
    int c = threadIdx.x & 127;
    int hh = threadIdx.x >> 7;
    float s = 0.f, sq = 0.f;
    for (int r = blockIdx.x * 2 + hh; r < NN; r += gridDim.x * 2) {
        float v = h[(size_t)r * C + c];
        s += v; sq = fmaf(v, v, sq);
    }
    __shared__ float ls[256], lq[256];
    ls[threadIdx.x] = s; lq[threadIdx.x] = sq;
    __syncthreads();
    if (hh == 0) {
        atomicAdd(&sums[c], s + ls[c + 128]);
        atomicAdd(&sums[128 + c], sq + lq[c + 128]);
    }
}

// ---------------- launch ----------------

extern "C" void kernel_launch(void* const* d_in, const int* in_sizes, int n_in,
                              void* d_out, int out_size, void* d_ws, size_t ws_size,
                              hipStream_t stream) {
    (void)in_sizes; (void)n_in; (void)out_size; (void)ws_size;
    const float* x      = (const float*)d_in[0];
    const int*   ei     = (const int*)d_in[1];
    const float* W1     = (const float*)d_in[2];
    // d_in[3] = b1: cancelled exactly by BN mean-subtraction
    const float* gamma1 = (const float*)d_in[4];
    const float* beta1  = (const float*)d_in[5];
    const float* W2     = (const float*)d_in[6];
    // d_in[7] = b2: cancelled exactly by BN
    const float* gamma2 = (const float*)d_in[8];
    const float* beta2  = (const float*)d_in[9];
    const float* Wmu    = (const float*)d_in[10];
    const float* bmu    = (const float*)d_in[11];
    const float* Wls    = (const float*)d_in[12];
    const float* bls    = (const float*)d_in[13];

    float* outmu = (float*)d_out;
    float* outls = outmu + (size_t)NN * OUTC;

    char* w = (char*)d_ws;
    size_t off = 0;
    auto alloc = [&](size_t bytes) { char* p = w + off; off = (off + bytes + 255) & ~(size_t)255; return p; };
    unsigned short* t = (unsigned short*)alloc(sizeof(unsigned short) * NN * C);  // 12.8 MB bf16
    float* aggb   = (float*)alloc(sizeof(float) * NN * C);       // 25.6 MB f32
    int*   cnt    = (int*)  alloc(sizeof(int) * NN);
    float* sums   = (float*)alloc(sizeof(float) * 512);          // adjacent to cnt: one memset covers both
    int*   rowptr = (int*)  alloc(sizeof(int) * (NN + 1));
    int*   wpos   = (int*)  alloc(sizeof(int) * NN);
    int*   col    = (int*)  alloc(sizeof(int) * NE);
    float* dinv   = (float*)alloc(sizeof(float) * NN);
    int*   bsum   = (int*)  alloc(sizeof(int) * 64);
    unsigned short* Wpk = (unsigned short*)alloc(sizeof(unsigned short) * 3 * 16384);  // 96 KB
    float* sumsA = sums; float* sumsB = sums + 256;

    const int* srcp = ei;
    const int* dstp = ei + NE;

    size_t zspan = (size_t)((char*)(sums + 512) - (char*)cnt);
    hipMemsetAsync(cnt, 0, zspan, stream);

    hist_kernel<<<(NE + 255) / 256, 256, 0, stream>>>(dstp, cnt);
    scan1_kernel<<<NBLK, 256, 0, stream>>>(cnt, rowptr, dinv, bsum);
    scan3_kernel<<<NBLK, 256, 0, stream>>>(bsum, rowptr, wpos);
    fill_kernel<<<(NE + 255) / 256, 256, 0, stream>>>(srcp, dstp, wpos, col);
    prep_kernel<<<24, 256, 0, stream>>>(W1, W2, Wmu, Wls, Wpk);

    const int GB = (NN + 31) / 32;
    const int AB = NN / 4;

    // layer 1: t = bf16(dinv .* (x@W1)) ; aggb = aggregate ; BN1 stats
    gemm_kernel<false><<<GB, 256, 0, stream>>>(x, Wpk, nullptr, nullptr, nullptr, dinv, t);
    agg_kernel<false><<<AB, 256, 0, stream>>>(t, rowptr, col, dinv, nullptr, nullptr, aggb, nullptr);
    bnstats_kernel<<<400, 256, 0, stream>>>(aggb, sumsA);

    // layer 2: t = bf16(dinv .* (relu(BN1(aggb))@W2)) ; aggb = aggregate ; BN2 stats
    gemm_kernel<true><<<GB, 256, 0, stream>>>(aggb, Wpk + 16384, sumsA, gamma1, beta1, dinv, t);
    agg_kernel<false><<<AB, 256, 0, stream>>>(t, rowptr, col, dinv, nullptr, nullptr, aggb, nullptr);
    bnstats_kernel<<<400, 256, 0, stream>>>(aggb, sumsB);

    // heads (reassociated): t = bf16(dinv .* (relu(BN2(aggb)) @ [Wmu|Wls])) ; agg3 -> split + bias
    gemm_kernel<true><<<GB, 256, 0, stream>>>(aggb, Wpk + 32768, sumsB, gamma2, beta2, dinv, t);
    agg_kernel<true><<<AB, 256, 0, stream>>>(t, rowptr, col, dinv, bmu, bls, outmu, outls);
}

// Round 7
// 396.431 us; speedup vs baseline: 1.8019x; 1.0294x over previous
//
#include <hip/hip_runtime.h>

#define NN 50000
#define NE 800000
#define C 128
#define OUTC 64
#define BN_EPS 1e-5f
#define INVN (1.0f / 50000.0f)
#define NBLK 49       // ceil(NN/1024)
#define NSH 8         // dst-range shards (= XCDs)
#define SHW (NN / NSH)      // 6250 dst rows per shard
#define NCHUNK 128
#define CHUNK (NE / NCHUNK) // 6250 edges per chunk

typedef __attribute__((ext_vector_type(8))) short bf16x8;
typedef __attribute__((ext_vector_type(4))) float f32x4;
typedef __attribute__((ext_vector_type(8))) unsigned short u16x8;

// round-to-nearest-even f32 -> bf16 (finite values)
__device__ __forceinline__ unsigned short f2bf(float f) {
    unsigned u = __float_as_uint(f);
    u += 0x7fffu + ((u >> 16) & 1u);
    return (unsigned short)(u >> 16);
}
__device__ __forceinline__ float bf2f(unsigned short s) {
    return __uint_as_float((unsigned)s << 16);
}

// ---------------- CSR build (XCD-sharded by dst range) ----------------
// Block b: shard g=b&7 (-> XCD g via round-robin), chunk m=b>>3.
// Only edges with dst in [g*SHW,(g+1)*SHW) are processed -> cnt/wpos atomics and
// col-line writes stay in one XCD's L2 (kills cross-XCD line ping-pong).

__global__ __launch_bounds__(256) void hist_kernel(const int* __restrict__ dstp, int* __restrict__ cnt) {
    int g = blockIdx.x & 7;
    int mb = blockIdx.x >> 3;
    int lo = g * SHW, hi = lo + SHW;
    int end = (mb + 1) * CHUNK;
    for (int e = mb * CHUNK + threadIdx.x; e < end; e += 256) {
        int d = dstp[e];
        if (d >= lo && d < hi) atomicAdd(&cnt[d], 1);
    }
}

__global__ __launch_bounds__(256) void fill_kernel(const int* __restrict__ srcp, const int* __restrict__ dstp,
                                                   int* __restrict__ wpos, int* __restrict__ col) {
    int g = blockIdx.x & 7;
    int mb = blockIdx.x >> 3;
    int lo = g * SHW, hi = lo + SHW;
    int end = (mb + 1) * CHUNK;
    for (int e = mb * CHUNK + threadIdx.x; e < end; e += 256) {
        int d = dstp[e];
        if (d >= lo && d < hi) {
            int p = atomicAdd(&wpos[d], 1);
            col[p] = srcp[e];
        }
    }
}

__global__ __launch_bounds__(256) void scan1_kernel(const int* __restrict__ cnt, int* __restrict__ rowptr,
                                                    float* __restrict__ dinv, int* __restrict__ bsum) {
    __shared__ int lds[256];
    int tid = threadIdx.x;
    int base = blockIdx.x * 1024 + tid * 4;
    int v[4];
    int s = 0;
    #pragma unroll
    for (int j = 0; j < 4; ++j) { int i = base + j; v[j] = (i < NN) ? cnt[i] : 0; s += v[j]; }
    lds[tid] = s;
    __syncthreads();
    for (int off = 1; off < 256; off <<= 1) {
        int x = (tid >= off) ? lds[tid - off] : 0;
        __syncthreads();
        lds[tid] += x;
        __syncthreads();
    }
    int excl = lds[tid] - s;
    #pragma unroll
    for (int j = 0; j < 4; ++j) {
        int i = base + j;
        if (i < NN) {
            rowptr[i] = excl;                       // local exclusive; block offset added in scan3
            dinv[i] = rsqrtf((float)(v[j] + 1));    // +1 self-loop
        }
        excl += v[j];
    }
    if (tid == 255) bsum[blockIdx.x] = lds[255];
}

// adds block offsets (inline 49-element scan of bsum), mirrors into wpos
__global__ __launch_bounds__(256) void scan3_kernel(const int* __restrict__ bsum, int* __restrict__ rowptr,
                                                    int* __restrict__ wpos) {
    __shared__ int boff;
    int tid = threadIdx.x;
    if (tid < 64) {
        int orig = (tid < NBLK) ? bsum[tid] : 0;
        int v = orig;
        #pragma unroll
        for (int off = 1; off < 64; off <<= 1) {
            int x = __shfl_up(v, off);
            if (tid >= off) v += x;
        }
        if (tid == (int)blockIdx.x) boff = v - orig;   // exclusive prefix at this block
    }
    __syncthreads();
    int off = boff;
    int base = blockIdx.x * 1024 + tid * 4;
    #pragma unroll
    for (int j = 0; j < 4; ++j) {
        int i = base + j;
        if (i < NN) { int r = rowptr[i] + off; rowptr[i] = r; wpos[i] = r; }
    }
    if (blockIdx.x == 0 && tid == 0) rowptr[NN] = NE;
}

// ---------------- W pre-pack: bf16, MFMA B-fragment layout ----------------
// Wpk[mat][kt(4)][nt(8)][lane(64)][8 bf16]: lane holds W[kt*32 + (lane>>4)*8 + j][nt*16 + (lane&15)]
// mat 0 = W1, 1 = W2, 2 = [Wmu|Wls]

__global__ __launch_bounds__(256) void prep_kernel(const float* __restrict__ W1, const float* __restrict__ W2,
                                                   const float* __restrict__ Wmu, const float* __restrict__ Wls,
                                                   unsigned short* __restrict__ Wpk) {
    int idx = blockIdx.x * 256 + threadIdx.x;    // 0..6143
    if (idx >= 3 * 2048) return;
    int which = idx >> 11;
    int r = idx & 2047;
    int l = r & 63;
    int nt = (r >> 6) & 7;
    int kt = r >> 9;
    int m = l & 15, kg = l >> 4;
    int c = nt * 16 + m;
    bf16x8 o;
    #pragma unroll
    for (int j = 0; j < 8; ++j) {
        int k = kt * 32 + kg * 8 + j;
        float w;
        if (which == 0)      w = W1[k * 128 + c];
        else if (which == 1) w = W2[k * 128 + c];
        else                 w = (c < 64) ? Wmu[k * 64 + c] : Wls[k * 64 + (c - 64)];
        o[j] = (short)f2bf(w);
    }
    *(bf16x8*)&Wpk[(size_t)which * 16384 + (size_t)r * 8] = o;
}

// ---------------- GEMM: [N x 128] @ [128 x 128] via bf16 MFMA, f32 accum ----------------
// TRANS: apply BN(from raw sums)+ReLU to A rows on load (f32), then cvt to bf16
// Output: t[row][c] = bf16(dinv[row] * acc)  (pre-scaled for pure-sum aggregation)
// Block: 32 rows, 4 waves = 2 row-halves x 2 col-halves. Wave: 16 rows x 64 cols.

template<bool TRANS>
__global__ __launch_bounds__(256) void gemm_kernel(
    const float* __restrict__ A, const unsigned short* __restrict__ Wpk,
    const float* __restrict__ sums, const float* __restrict__ gamma, const float* __restrict__ beta,
    const float* __restrict__ dinv, unsigned short* __restrict__ out)
{
    int tid = threadIdx.x;
    int wv = tid >> 6, l = tid & 63;
    int m = l & 15, kg = l >> 4;
    int rhalf = wv & 1, chalf = wv >> 1;
    int row = blockIdx.x * 32 + rhalf * 16 + m;
    int rowc = min(row, NN - 1);
    const float* Ar = A + (size_t)rowc * C;

    f32x4 acc[4] = {};

    #pragma unroll
    for (int kt = 0; kt < 4; ++kt) {
        int k0 = kt * 32 + kg * 8;
        float4 x0 = *(const float4*)&Ar[k0];
        float4 x1 = *(const float4*)&Ar[k0 + 4];
        float av[8] = {x0.x, x0.y, x0.z, x0.w, x1.x, x1.y, x1.z, x1.w};
        if (TRANS) {
            #pragma unroll
            for (int j = 0; j < 8; ++j) {
                int k = k0 + j;
                float mean = sums[k] * INVN;
                float var = fmaf(-mean, mean, sums[128 + k] * INVN);
                float sc = gamma[k] * rsqrtf(var + BN_EPS);
                float sh = fmaf(-mean, sc, beta[k]);
                av[j] = fmaxf(fmaf(av[j], sc, sh), 0.f);
            }
        }
        bf16x8 af;
        #pragma unroll
        for (int j = 0; j < 8; ++j) af[j] = (short)f2bf(av[j]);
        #pragma unroll
        for (int n = 0; n < 4; ++n) {
            int nt = chalf * 4 + n;
            bf16x8 bfr = *(const bf16x8*)&Wpk[(size_t)((kt * 8 + nt) * 64 + l) * 8];
            acc[n] = __builtin_amdgcn_mfma_f32_16x16x32_bf16(af, bfr, acc[n], 0, 0, 0);
        }
    }

    // D: lane l holds D[(l>>4)*4 + r][nt*16 + (l&15)]
    int ro = blockIdx.x * 32 + rhalf * 16 + kg * 4;
    #pragma unroll
    for (int r = 0; r < 4; ++r) {
        int orow = ro + r;
        if (orow < NN) {
            float di = dinv[orow];
            #pragma unroll
            for (int n = 0; n < 4; ++n)
                out[(size_t)orow * C + (chalf * 4 + n) * 16 + m] = f2bf(di * acc[n][r]);
        }
    }
}

// ---------------- Pull aggregation from bf16 table, 4 edges per gather instr ----------------
// Wave per row. lane = eg(=l>>4: edge slot) x q(=l&15: channel-8th, ch q*8..q*8+7).
// Per batch of 16 edges: 4 gathers of ushort8 (16B/lane, 1KB/instr = 4 edge-rows).
// Load phase separated from fma phase so 4 gathers are in flight.
// !SPLIT: out f32 [NN][128].  SPLIT: heads - split 64|64 + bias.

template<bool SPLIT>
__global__ __launch_bounds__(256) void agg_kernel(
    const unsigned short* __restrict__ t, const int* __restrict__ rowptr, const int* __restrict__ col,
    const float* __restrict__ dinv, const float* __restrict__ bmu, const float* __restrict__ bls,
    float* __restrict__ outb, float* __restrict__ out2)
{
    int wave = threadIdx.x >> 6, lane = threadIdx.x & 63;
    int row = blockIdx.x * 4 + wave;     // NN % 4 == 0: no guard
    int q = lane & 15, eg = lane >> 4;
    const unsigned short* tq = t + q * 8;
    int e0 = rowptr[row], e1 = rowptr[row + 1];
    float a[8] = {};

    for (int e = e0; e < e1; e += 16) {
        int lim = e1 - 1;
        u16x8 v[4];
        float msk[4];
        #pragma unroll
        for (int b = 0; b < 4; ++b) {
            int i = e + b * 4 + eg;
            msk[b] = (i < e1) ? 1.f : 0.f;
            if (e + b * 4 < e1) {                       // wave-uniform batch-live check
                int s = col[min(i, lim)];
                v[b] = *(const u16x8*)&tq[(size_t)s * C];
            } else {
                v[b] = (u16x8)0;
                msk[b] = 0.f;
            }
        }
        #pragma unroll
        for (int b = 0; b < 4; ++b) {
            #pragma unroll
            for (int j = 0; j < 8; ++j)
                a[j] = fmaf(msk[b], bf2f(v[b][j]), a[j]);
        }
    }

    {   // self-loop: counted once (eg==0 lanes only)
        u16x8 vs = *(const u16x8*)&tq[(size_t)row * C];
        float ms = (eg == 0) ? 1.f : 0.f;
        #pragma unroll
        for (int j = 0; j < 8; ++j)
            a[j] = fmaf(ms, bf2f(vs[j]), a[j]);
    }

    #pragma unroll
    for (int j = 0; j < 8; ++j) {
        a[j] += __shfl_xor(a[j], 16);
        a[j] += __shfl_xor(a[j], 32);
    }

    if (eg == 0) {
        float di = dinv[row];
        int c = q * 8;
        if (!SPLIT) {
            *(float4*)&outb[(size_t)row * C + c]     = make_float4(di*a[0], di*a[1], di*a[2], di*a[3]);
            *(float4*)&outb[(size_t)row * C + c + 4] = make_float4(di*a[4], di*a[5], di*a[6], di*a[7]);
        } else {
            if (c < 64) {
                float4 b0 = *(const float4*)&bmu[c];
                float4 b1 = *(const float4*)&bmu[c + 4];
                *(float4*)&outb[(size_t)row * OUTC + c]
                    = make_float4(fmaf(di,a[0],b0.x), fmaf(di,a[1],b0.y), fmaf(di,a[2],b0.z), fmaf(di,a[3],b0.w));
                *(float4*)&outb[(size_t)row * OUTC + c + 4]
                    = make_float4(fmaf(di,a[4],b1.x), fmaf(di,a[5],b1.y), fmaf(di,a[6],b1.z), fmaf(di,a[7],b1.w));
            } else {
                int cc = c - 64;
                float4 b0 = *(const float4*)&bls[cc];
                float4 b1 = *(const float4*)&bls[cc + 4];
                *(float4*)&out2[(size_t)row * OUTC + cc]
                    = make_float4(fmaf(di,a[0],b0.x), fmaf(di,a[1],b0.y), fmaf(di,a[2],b0.z), fmaf(di,a[3],b0.w));
                *(float4*)&out2[(size_t)row * OUTC + cc + 4]
                    = make_float4(fmaf(di,a[4],b1.x), fmaf(di,a[5],b1.y), fmaf(di,a[6],b1.z), fmaf(di,a[7],b1.w));
            }
        }
    }
}

// ---------------- BatchNorm stats (f32 row-major input) ----------------

__global__ __launch_bounds__(256) void bnstats_kernel(const float* __restrict__ h, float* __restrict__ sums) {
    int c = threadIdx.x & 127;
    int hh = threadIdx.x >> 7;
    float s = 0.f, sq = 0.f;
    for (int r = blockIdx.x * 2 + hh; r < NN; r += gridDim.x * 2) {
        float v = h[(size_t)r * C + c];
        s += v; sq = fmaf(v, v, sq);
    }
    __shared__ float ls[256], lq[256];
    ls[threadIdx.x] = s; lq[threadIdx.x] = sq;
    __syncthreads();
    if (hh == 0) {
        atomicAdd(&sums[c], s + ls[c + 128]);
        atomicAdd(&sums[128 + c], sq + lq[c + 128]);
    }
}

// ---------------- launch ----------------

extern "C" void kernel_launch(void* const* d_in, const int* in_sizes, int n_in,
                              void* d_out, int out_size, void* d_ws, size_t ws_size,
                              hipStream_t stream) {
    (void)in_sizes; (void)n_in; (void)out_size; (void)ws_size;
    const float* x      = (const float*)d_in[0];
    const int*   ei     = (const int*)d_in[1];
    const float* W1     = (const float*)d_in[2];
    // d_in[3] = b1: cancelled exactly by BN mean-subtraction
    const float* gamma1 = (const float*)d_in[4];
    const float* beta1  = (const float*)d_in[5];
    const float* W2     = (const float*)d_in[6];
    // d_in[7] = b2: cancelled exactly by BN
    const float* gamma2 = (const float*)d_in[8];
    const float* beta2  = (const float*)d_in[9];
    const float* Wmu    = (const float*)d_in[10];
    const float* bmu    = (const float*)d_in[11];
    const float* Wls    = (const float*)d_in[12];
    const float* bls    = (const float*)d_in[13];

    float* outmu = (float*)d_out;
    float* outls = outmu + (size_t)NN * OUTC;

    char* w = (char*)d_ws;
    size_t off = 0;
    auto alloc = [&](size_t bytes) { char* p = w + off; off = (off + bytes + 255) & ~(size_t)255; return p; };
    unsigned short* t = (unsigned short*)alloc(sizeof(unsigned short) * NN * C);  // 12.8 MB bf16
    float* aggb   = (float*)alloc(sizeof(float) * NN * C);       // 25.6 MB f32
    int*   cnt    = (int*)  alloc(sizeof(int) * NN);
    float* sums   = (float*)alloc(sizeof(float) * 512);          // adjacent to cnt: one memset covers both
    int*   rowptr = (int*)  alloc(sizeof(int) * (NN + 1));
    int*   wpos   = (int*)  alloc(sizeof(int) * NN);
    int*   col    = (int*)  alloc(sizeof(int) * NE);
    float* dinv   = (float*)alloc(sizeof(float) * NN);
    int*   bsum   = (int*)  alloc(sizeof(int) * 64);
    unsigned short* Wpk = (unsigned short*)alloc(sizeof(unsigned short) * 3 * 16384);  // 96 KB
    float* sumsA = sums; float* sumsB = sums + 256;

    const int* srcp = ei;
    const int* dstp = ei + NE;

    size_t zspan = (size_t)((char*)(sums + 512) - (char*)cnt);
    hipMemsetAsync(cnt, 0, zspan, stream);

    hist_kernel<<<NSH * NCHUNK, 256, 0, stream>>>(dstp, cnt);
    scan1_kernel<<<NBLK, 256, 0, stream>>>(cnt, rowptr, dinv, bsum);
    scan3_kernel<<<NBLK, 256, 0, stream>>>(bsum, rowptr, wpos);
    fill_kernel<<<NSH * NCHUNK, 256, 0, stream>>>(srcp, dstp, wpos, col);
    prep_kernel<<<24, 256, 0, stream>>>(W1, W2, Wmu, Wls, Wpk);

    const int GB = (NN + 31) / 32;
    const int AB = NN / 4;

    // layer 1: t = bf16(dinv .* (x@W1)) ; aggb = aggregate ; BN1 stats
    gemm_kernel<false><<<GB, 256, 0, stream>>>(x, Wpk, nullptr, nullptr, nullptr, dinv, t);
    agg_kernel<false><<<AB, 256, 0, stream>>>(t, rowptr, col, dinv, nullptr, nullptr, aggb, nullptr);
    bnstats_kernel<<<400, 256, 0, stream>>>(aggb, sumsA);

    // layer 2: t = bf16(dinv .* (relu(BN1(aggb))@W2)) ; aggb = aggregate ; BN2 stats
    gemm_kernel<true><<<GB, 256, 0, stream>>>(aggb, Wpk + 16384, sumsA, gamma1, beta1, dinv, t);
    agg_kernel<false><<<AB, 256, 0, stream>>>(t, rowptr, col, dinv, nullptr, nullptr, aggb, nullptr);
    bnstats_kernel<<<400, 256, 0, stream>>>(aggb, sumsB);

    // heads (reassociated): t = bf16(dinv .* (relu(BN2(aggb)) @ [Wmu|Wls])) ; agg3 -> split + bias
    gemm_kernel<true><<<GB, 256, 0, stream>>>(aggb, Wpk + 32768, sumsB, gamma2, beta2, dinv, t);
    agg_kernel<true><<<AB, 256, 0, stream>>>(t, rowptr, col, dinv, bmu, bls, outmu, outls);
}